// Round 1
// baseline (28.581 us; speedup 1.0000x reference)
//
#include <hip/hip_runtime.h>
#include <hip/hip_bf16.h>

// Kernel 1: one block per row. Compute trapz integral of (y_pred - y_true)
// over [0, idx[b]] with unit spacing, write err_sq[b] = (integral)^2 to ws.
__global__ __launch_bounds__(256) void row_integral_kernel(
    const float* __restrict__ yp, const float* __restrict__ yt,
    const int* __restrict__ fidx, float* __restrict__ err_sq, int N) {
    const int b = blockIdx.x;
    const float* __restrict__ p = yp + (size_t)b * N;
    const float* __restrict__ t = yt + (size_t)b * N;
    const int id = fidx[b];

    float sum = 0.0f;
    if (id > 0) {
        // need elements j in [0, id]; weights: 0.5 at j==0 and j==id, 1.0 inside
        const int nchunk = (id >> 2) + 1;  // float4 chunks covering 0..id
        const float4* __restrict__ p4 = (const float4*)p;
        const float4* __restrict__ t4 = (const float4*)t;
        for (int c = threadIdx.x; c < nchunk; c += 256) {
            const int j0 = c << 2;
            float4 a = p4[c];
            float4 q = t4[c];
            float d0 = a.x - q.x;
            float d1 = a.y - q.y;
            float d2 = a.z - q.z;
            float d3 = a.w - q.w;
            float s = 0.0f;
            int j = j0;
            if (j <= id) s += (j == 0 || j == id) ? 0.5f * d0 : d0;
            j = j0 + 1;
            if (j <= id) s += (j == id) ? 0.5f * d1 : d1;
            j = j0 + 2;
            if (j <= id) s += (j == id) ? 0.5f * d2 : d2;
            j = j0 + 3;
            if (j <= id) s += (j == id) ? 0.5f * d3 : d3;
            sum += s;
        }
    }

    // wave64 reduce
    for (int o = 32; o > 0; o >>= 1) sum += __shfl_down(sum, o);

    __shared__ float part[4];
    const int lane = threadIdx.x & 63;
    const int wid = threadIdx.x >> 6;
    if (lane == 0) part[wid] = sum;
    __syncthreads();
    if (threadIdx.x == 0) {
        float total = part[0] + part[1] + part[2] + part[3];
        err_sq[b] = total * total;
    }
}

// Kernel 2: single block, deterministic reduction of B floats -> mean.
__global__ __launch_bounds__(1024) void reduce_mean_kernel(
    const float* __restrict__ err_sq, float* __restrict__ out, int B) {
    float s = 0.0f;
    for (int i = threadIdx.x; i < B; i += 1024) s += err_sq[i];
    for (int o = 32; o > 0; o >>= 1) s += __shfl_down(s, o);
    __shared__ float part[16];
    const int lane = threadIdx.x & 63;
    const int wid = threadIdx.x >> 6;
    if (lane == 0) part[wid] = s;
    __syncthreads();
    if (threadIdx.x == 0) {
        float total = 0.0f;
        for (int w = 0; w < 16; ++w) total += part[w];
        out[0] = total / (float)B;
    }
}

extern "C" void kernel_launch(void* const* d_in, const int* in_sizes, int n_in,
                              void* d_out, int out_size, void* d_ws, size_t ws_size,
                              hipStream_t stream) {
    const float* yp = (const float*)d_in[0];
    const float* yt = (const float*)d_in[1];
    const int* fidx = (const int*)d_in[2];
    float* out = (float*)d_out;
    float* err_sq = (float*)d_ws;

    const int B = in_sizes[2];           // 8192
    const int N = in_sizes[0] / B;       // 4096

    row_integral_kernel<<<B, 256, 0, stream>>>(yp, yt, fidx, err_sq, N);
    reduce_mean_kernel<<<1, 1024, 0, stream>>>(err_sq, out, B);
}